// Round 7
// baseline (166.399 us; speedup 1.0000x reference)
//
#include <hip/hip_runtime.h>
#include <math.h>

#define BS   8
#define NPTS 2048
#define CCH  12      // channels per flow
#define NF   2       // flow dim
#define DIM  24      // NF*CCH, feats order: d = f*12 + c
#define KTOP 16

#define NROWS    (BS * NPTS)
#define TGT_BASE (NROWS * KTOP * CCH)   // 3145728

#define WPB   4      // waves per topk block (256 threads)

typedef unsigned long long u64;
typedef unsigned int       u32;

// ws layout (bytes): feats [NROWS][DIM] | raw [NROWS][CCH] | part [NROWS][SPLIT][KTOP]
#define WS_FEATS 0
#define WS_RAW   (NROWS * DIM * 4)                 // 1572864
#define WS_PART  (WS_RAW + NROWS * CCH * 4)        // 2359296 (8B aligned)

// Emulate np.linalg.norm(v) + 1e-8 in float32 exactly (numpy pairwise sum, n=24):
//   r[j] = (s[j] + s[j+8]) + s[j+16];  res = ((r0+r1)+(r2+r3)) + ((r4+r5)+(r6+r7))
__device__ __forceinline__ float np_norm_den(const float* __restrict__ v)
{
#pragma clang fp contract(off)
    float s[DIM];
    #pragma unroll
    for (int d = 0; d < DIM; ++d) s[d] = v[d] * v[d];
    float r[8];
    #pragma unroll
    for (int j = 0; j < 8; ++j) r[j] = (s[j] + s[j + 8]) + s[j + 16];
    float res = ((r[0] + r[1]) + (r[2] + r[3])) + ((r[4] + r[5]) + (r[6] + r[7]));
    return sqrtf(res) + 1e-8f;
}

// Monotone float -> u32 (preserves total order for finite floats)
__device__ __forceinline__ u32 ordf(float f)
{
    u32 u = __float_as_uint(f);
    return ((int)u >= 0) ? (u | 0x80000000u) : ~u;
}

// ---------------------------------------------------------------------------
// Kernel 0: normalize every row (numpy-exact fp32), write contiguous feats,
// raw flow-slice (gather-friendly), and the tgt_out output.
// ---------------------------------------------------------------------------
__global__ __launch_bounds__(256) void prep_kernel(
    const float* __restrict__ x_c,     // [8][12][2][2048]
    const int*   __restrict__ flow_p,
    float*       __restrict__ feats,   // [NROWS][DIM] normalized
    float*       __restrict__ raw,     // [NROWS][CCH] raw flow slice
    float*       __restrict__ out)
{
    const int t = blockIdx.x * 256 + threadIdx.x;   // global row
    const int b = t >> 11;
    const int n = t & (NPTS - 1);
    const float* xb = x_c + (size_t)b * CCH * NF * NPTS;

    float v[DIM];
    {
#pragma clang fp contract(off)
        #pragma unroll
        for (int c = 0; c < CCH; ++c)
            #pragma unroll
            for (int f = 0; f < NF; ++f)
                v[f * CCH + c] = xb[(c * NF + f) * NPTS + n];

        const float den = np_norm_den(v);
        float* fo = feats + (size_t)t * DIM;
        #pragma unroll
        for (int d = 0; d < DIM; ++d) fo[d] = v[d] / den;
    }

    const int flow = flow_p[0];
    float* ro = raw + (size_t)t * CCH;
    #pragma unroll
    for (int c = 0; c < CCH; ++c) {
        const float xv = flow ? v[CCH + c] : v[c];   // raw value, pre-norm
        ro[c] = xv;
        out[TGT_BASE + ((size_t)b * CCH + c) * NPTS + n] = xv;   // tgt_out
    }
}

// ---------------------------------------------------------------------------
// Kernel 1: per-row partial top-16. Block = (b, 64-row chunk, split s).
// 256 thr = 4 waves; lane = row. Wave w streams cpw = 2048/SPLIT/4 candidates
// from a wave-uniform base (candidate data identical across lanes). Dot =
// 24 sequential v_fma_f32 — exact fp32 chain. Batch-16 branchless bitonic
// maintains the sorted-desc u64-key top-16 fully in registers
// (NO launch_bounds occupancy cap -> no spill/AGPR-parking of sort state).
// ---------------------------------------------------------------------------
__global__ __launch_bounds__(256) void topk_kernel(
    const float* __restrict__ feats,
    u64*         __restrict__ part,    // [NROWS][SPLIT][KTOP]
    int SPLIT)
{
    __shared__ u64 keys[WPB][KTOP][64];   // 32 KiB, epilogue only

    const int tid  = threadIdx.x;
    const int lane = tid & 63;
    const int w    = __builtin_amdgcn_readfirstlane(tid >> 6);  // uniform wave id
    int bi = blockIdx.x;
    const int s     = bi % SPLIT; bi /= SPLIT;
    const int chunk = bi & 31;
    const int b     = bi >> 5;
    const int row   = b * NPTS + chunk * 64 + lane;

    // own row's normalized vector (per-lane)
    float rfn[DIM];
    {
        const float* fr = feats + (size_t)row * DIM;
        #pragma unroll
        for (int d = 0; d < DIM; ++d) rfn[d] = fr[d];
    }

    // sorted-descending top-16 packed keys; sentinel 0 < any real key
    u64 list[KTOP];
    #pragma unroll
    for (int k = 0; k < KTOP; ++k) list[k] = 0ull;

    const int    cpw = (NPTS / SPLIT) / WPB;
    const int    mg0 = s * (NPTS / SPLIT) + w * cpw;
    const float* cb  = feats + ((size_t)b * NPTS + mg0) * DIM;  // uniform base

    for (int jb = 0; jb < cpw; jb += 16) {
        u64 bkey[KTOP];
        #pragma unroll 4
        for (int jj = 0; jj < 16; ++jj) {
            const float* cp = cb + (size_t)(jb + jj) * DIM;   // wave-uniform
            float acc = 0.0f;
            #pragma unroll
            for (int d = 0; d < DIM; ++d)
                acc = __builtin_fmaf(cp[d], rfn[d], acc);     // exact chain
            const int mg = mg0 + jb + jj;
            bkey[jj] = ((u64)ordf(acc) << 32) | (u32)(2047 - mg);
        }
        // bitonic sort batch ASCENDING (branchless, fully unrolled)
        #pragma unroll
        for (int k = 2; k <= 16; k <<= 1)
            #pragma unroll
            for (int j = k >> 1; j > 0; j >>= 1)
                #pragma unroll
                for (int i = 0; i < 16; ++i) {
                    const int l = i | j;
                    if (l > i) {
                        const bool up = ((i & k) == 0);
                        const u64 a = bkey[i], bv = bkey[l];
                        const bool sw = up ? (a > bv) : (a < bv);
                        bkey[i] = sw ? bv : a;
                        bkey[l] = sw ? a : bv;
                    }
                }
        // merge: list desc + batch asc -> elementwise max is bitonic
        #pragma unroll
        for (int i = 0; i < 16; ++i) {
            const u64 a = list[i], bv = bkey[i];
            list[i] = (a > bv) ? a : bv;
        }
        // bitonic cleanup -> sorted descending
        #pragma unroll
        for (int j = 8; j > 0; j >>= 1)
            #pragma unroll
            for (int i = 0; i < 16; ++i) {
                const int l = i | j;
                if (l > i) {
                    const u64 a = list[i], bv = list[l];
                    const bool sw = (a < bv);
                    list[i] = sw ? bv : a;
                    list[l] = sw ? a : bv;
                }
            }
    }

    #pragma unroll
    for (int k = 0; k < KTOP; ++k) keys[w][k][lane] = list[k];
    __syncthreads();

    // per-row 4-way merge of sorted lists -> sorted 16-list, write to ws
    if (tid < 64) {
        int h0 = 0, h1 = 0, h2 = 0, h3 = 0;
        const int rg = b * NPTS + chunk * 64 + tid;
        u64* dst = part + ((size_t)rg * SPLIT + s) * KTOP;
        for (int k = 0; k < KTOP; ++k) {
            u64 best = 0; int bq = 0;
            u64 v0 = keys[0][h0][tid];
            u64 v1 = keys[1][h1][tid];
            u64 v2 = keys[2][h2][tid];
            u64 v3 = keys[3][h3][tid];
            if (v0 > best) { best = v0; bq = 0; }
            if (v1 > best) { best = v1; bq = 1; }
            if (v2 > best) { best = v2; bq = 2; }
            if (v3 > best) { best = v3; bq = 3; }
            h0 += (bq == 0); h1 += (bq == 1); h2 += (bq == 2); h3 += (bq == 3);
            dst[k] = best;
        }
    }
}

// ---------------------------------------------------------------------------
// Kernel 2: merge the SPLIT sorted lists per row, gather sx_c from the
// contiguous raw flow-slice. Block = 16 rows, 256 threads, grid 1024.
// ---------------------------------------------------------------------------
__global__ __launch_bounds__(256) void gather_kernel(
    const float* __restrict__ raw,     // [NROWS][CCH]
    const u64*   __restrict__ part,
    float*       __restrict__ out,
    int SPLIT)
{
    __shared__ u64 kk[16 * 4 * KTOP];   // max 8 KiB
    __shared__ int sel[16][KTOP];

    const int tid  = threadIdx.x;
    const int rb   = blockIdx.x * 16;       // first global row of this block
    const int b    = rb >> 11;              // same batch for all 16 rows
    const int nper = SPLIT * KTOP;

    for (int i = tid; i < 16 * nper; i += 256)
        kk[i] = part[(size_t)rb * nper + i];
    __syncthreads();

    if (tid < 16) {
        const u64* rk = &kk[tid * nper];
        int h0 = 0, h1 = 0, h2 = 0, h3 = 0;
        for (int k = 0; k < KTOP; ++k) {
            u64 best = 0; int bq = 0;
            u64 v0 = rk[h0];
            if (v0 > best) { best = v0; bq = 0; }
            if (SPLIT > 1) {
                u64 v1 = rk[KTOP + h1];
                if (v1 > best) { best = v1; bq = 1; }
            }
            if (SPLIT > 2) {
                u64 v2 = rk[2 * KTOP + h2];
                if (v2 > best) { best = v2; bq = 2; }
                u64 v3 = rk[3 * KTOP + h3];
                if (v3 > best) { best = v3; bq = 3; }
            }
            h0 += (bq == 0); h1 += (bq == 1); h2 += (bq == 2); h3 += (bq == 3);
            sel[tid][k] = 2047 - (int)(best & 0xFFFFFFFFull);
        }
    }
    __syncthreads();

    // sx_c[b, n, k, c] = raw[(b*2048 + sel)*12 + c]  (contiguous 12 floats)
    for (int e = tid; e < 16 * KTOP * CCH; e += 256) {
        const int L = e / (KTOP * CCH);
        const int r = e % (KTOP * CCH);
        const int k = r / CCH;
        const int c = r % CCH;
        out[((size_t)(rb + L) * KTOP + k) * CCH + c] =
            raw[((size_t)b * NPTS + sel[L][k]) * CCH + c];
    }
}

// ---------------------------------------------------------------------------
extern "C" void kernel_launch(void* const* d_in, const int* in_sizes, int n_in,
                              void* d_out, int out_size, void* d_ws, size_t ws_size,
                              hipStream_t stream)
{
    const float* x_c    = (const float*)d_in[0];
    const int*   flow_p = (const int*)d_in[1];
    float*       out    = (float*)d_out;

    float* feats = (float*)((char*)d_ws + WS_FEATS);
    float* raw   = (float*)((char*)d_ws + WS_RAW);
    u64*   part  = (u64*)  ((char*)d_ws + WS_PART);

    // pick largest SPLIT whose 'part' fits the workspace
    int SPLIT = 1;
    if (ws_size >= WS_PART + (size_t)NROWS * 4 * KTOP * 8) SPLIT = 4;
    else if (ws_size >= WS_PART + (size_t)NROWS * 2 * KTOP * 8) SPLIT = 2;

    prep_kernel<<<NROWS / 256, 256, 0, stream>>>(x_c, flow_p, feats, raw, out);
    topk_kernel<<<BS * 32 * SPLIT, 256, 0, stream>>>(feats, part, SPLIT);
    gather_kernel<<<NROWS / 16, 256, 0, stream>>>(raw, part, out, SPLIT);
}